// Round 13
// baseline (1049.297 us; speedup 1.0000x reference)
//
#include <hip/hip_runtime.h>
#include <math.h>

#define NFEAT 512
#define NHID  128
#define GRID  512
#define BLK   256
#define AGG_LB 1024      // logical agg blocks; slice = b&3
#define NSTREAMS 16384

typedef __attribute__((ext_vector_type(8))) short short8;
typedef __attribute__((ext_vector_type(4))) float f32x4;

static __device__ __forceinline__ ushort f2b(float f) {
    union { float f; uint u; } v; v.f = f;
    uint r = v.u + 0x7FFFu + ((v.u >> 16) & 1u);   // round-to-nearest-even
    return (ushort)(r >> 16);
}
static __device__ __forceinline__ float b2f_lo(uint bits) {
    union { uint u; float f; } v; v.u = bits << 16; return v.f;
}
static __device__ __forceinline__ float b2f_hi(uint bits) {
    union { uint u; float f; } v; v.u = bits & 0xffff0000u; return v.f;
}

struct Params {
    const float* x; const int* src; const int* dst;
    const float* W1; const float* b1; const float* W2; const float* b2;
    const float* Wc; const float* bc;
    float* out;
    uint* bar; int* deg; float* dinv; int* eoffs; int* ticket;
    uint* colp32; int* rankgs; int* bsum;
    ushort* W1T; ushort* W2T; ushort* hs; ushort* g1; ushort* g2;
    int N, E, S, nbch, gtiles;
};

// ---- software grid barrier: monotonic epoch, arrivals accumulate (no reset race) ----
static __device__ __forceinline__ void gsync(uint* bar, uint& ep) {
    __syncthreads();
    if (threadIdx.x == 0) {
        __threadfence();   // release: my block's writes -> device scope
        uint target = ep + 1;
        uint old = __hip_atomic_fetch_add(&bar[0], 1u, __ATOMIC_ACQ_REL, __HIP_MEMORY_SCOPE_AGENT);
        if (old == (uint)GRID * target - 1u) {
            __hip_atomic_store(&bar[16], target, __ATOMIC_RELEASE, __HIP_MEMORY_SCOPE_AGENT);
        } else {
            while (__hip_atomic_load(&bar[16], __ATOMIC_ACQUIRE, __HIP_MEMORY_SCOPE_AGENT) < target) {
                __builtin_amdgcn_s_sleep(1);
            }
        }
        __threadfence();   // acquire: invalidate stale caches
        ep = target;
    }
    __syncthreads();
}

// ---------------- GEMM phase (64x128 tile, grid-stride over tiles) ----------------
// Hs layout: [slice(4)][node(M)][32 feats] bf16, pre-scaled by rowscale[row].

template<int A_F32>
static __device__ void gemm_phase(const void* __restrict__ Aptr, const ushort* __restrict__ WT,
                                  const float* __restrict__ rowscale, ushort* __restrict__ Hs,
                                  int M, int K, int gtiles, char* smem) {
    ushort (*As)[40] = (ushort(*)[40])smem;                 // 64 x 40
    ushort (*Bs)[40] = (ushort(*)[40])(smem + 64 * 40 * 2); // 128 x 40

    const int tid = threadIdx.x;
    const int wc = tid >> 6, lane = tid & 63;
    const int lr = lane & 15, lk = (lane >> 4) * 8;
    const int sr = tid >> 2;
    const int sh = (tid & 3) * 8;

    for (int tb = blockIdx.x; tb < gtiles; tb += GRID) {
        const int rowbase = tb * 64;
        f32x4 acc[4][2];
#pragma unroll
        for (int i = 0; i < 4; i++)
#pragma unroll
            for (int j = 0; j < 2; j++) acc[i][j] = (f32x4)0.f;

        for (int k0 = 0; k0 < K; k0 += 32) {
            {
                int gr = rowbase + sr;
                ushort tmp[8];
                if (A_F32) {
                    const float* A = (const float*)Aptr;
                    if (gr < M) {
                        const float* p = A + (size_t)gr * K + k0 + sh;
#pragma unroll
                        for (int q = 0; q < 2; q++) {
                            float4 v = *(const float4*)(p + q * 4);
                            tmp[q * 4 + 0] = f2b(v.x); tmp[q * 4 + 1] = f2b(v.y);
                            tmp[q * 4 + 2] = f2b(v.z); tmp[q * 4 + 3] = f2b(v.w);
                        }
                    } else {
#pragma unroll
                        for (int q = 0; q < 8; q++) tmp[q] = 0;
                    }
                } else {
                    const ushort* A = (const ushort*)Aptr;
                    if (gr < M) {
                        *(short8*)&tmp[0] = *(const short8*)(A + (size_t)gr * K + k0 + sh);
                    } else {
#pragma unroll
                        for (int q = 0; q < 8; q++) tmp[q] = 0;
                    }
                }
                *(short8*)&As[sr][sh] = *(short8*)&tmp[0];
            }
            {
#pragma unroll
                for (int t = 0; t < 2; t++) {
                    int c = tid + t * 256;
                    int row = c >> 2, q = c & 3;
                    short8 v = *(const short8*)(WT + (size_t)row * K + k0 + q * 8);
                    *(short8*)&Bs[row][q * 8] = v;
                }
            }
            __syncthreads();

            short8 af[4], bfv[2];
#pragma unroll
            for (int i = 0; i < 4; i++) af[i] = *(const short8*)&As[i * 16 + lr][lk];
#pragma unroll
            for (int j = 0; j < 2; j++) bfv[j] = *(const short8*)&Bs[wc * 32 + j * 16 + lr][lk];
#pragma unroll
            for (int i = 0; i < 4; i++)
#pragma unroll
                for (int j = 0; j < 2; j++)
                    acc[i][j] = __builtin_amdgcn_mfma_f32_16x16x32_bf16(af[i], bfv[j], acc[i][j], 0, 0, 0);
            __syncthreads();
        }

#pragma unroll
        for (int i = 0; i < 4; i++) {
#pragma unroll
            for (int r = 0; r < 4; r++) {
                int row = rowbase + i * 16 + (lane >> 4) * 4 + r;
                if (row < M) {
                    float sc = rowscale[row];
#pragma unroll
                    for (int j = 0; j < 2; j++) {
                        int f = j * 16 + lr;
                        Hs[((size_t)wc * M + row) * 32 + f] = f2b(acc[i][j][r] * sc);
                    }
                }
            }
        }
    }
}

// ---------------- aggregation phase (stream-parallel, depth-4 pipeline) ----------------

static __device__ void aggs_phase(const ushort* __restrict__ hs, const uint* __restrict__ colp32,
                                  const int* __restrict__ rankgs, const float* __restrict__ dinv,
                                  const float* __restrict__ bias, ushort* __restrict__ outp,
                                  int n) {
    const int wid = threadIdx.x >> 6, lane = threadIdx.x & 63;
    const int st16 = lane >> 2, q = lane & 3;

    for (int b = blockIdx.x; b < AGG_LB; b += GRID) {
        const int s = b & 3;
        const int stream = (((b >> 2) << 2) + wid) * 16 + st16;
        int g = rankgs[stream];
        int se = rankgs[stream + 1];
        bool alive = g < se;
        if (!alive) g = 0;

        const ushort* hsl = hs + (size_t)s * n * 32;
        const float4 bv0 = *(const float4*)(bias + s * 32 + q * 8);
        const float4 bv1 = *(const float4*)(bias + s * 32 + q * 8 + 4);

        const uint* cp = colp32 + g;
        uint cw0 = cp[0], cw1 = cp[1], cw2 = cp[2], cw3 = cp[3];
        uint4 pk0 = *(const uint4*)(hsl + (size_t)(cw0 & 0xffffu) * 32 + q * 8);
        uint4 pk1 = *(const uint4*)(hsl + (size_t)(cw1 & 0xffffu) * 32 + q * 8);
        uint4 pk2 = *(const uint4*)(hsl + (size_t)(cw2 & 0xffffu) * 32 + q * 8);
        float fdv0 = (cw0 >> 16) ? dinv[(cw0 >> 16) - 1] : 0.f;
        float fdv1 = (cw1 >> 16) ? dinv[(cw1 >> 16) - 1] : 0.f;
        float fdv2 = (cw2 >> 16) ? dinv[(cw2 >> 16) - 1] : 0.f;
        float a0 = 0.f, a1 = 0.f, a2 = 0.f, a3 = 0.f;
        float a4 = 0.f, a5 = 0.f, a6 = 0.f, a7 = 0.f;

        while (__any(alive)) {
            if (alive) {
                uint cw4 = cp[4];
                uint4 pk3 = *(const uint4*)(hsl + (size_t)(cw3 & 0xffffu) * 32 + q * 8);
                float fdv3 = (cw3 >> 16) ? dinv[(cw3 >> 16) - 1] : 0.f;

                a0 += b2f_lo(pk0.x); a1 += b2f_hi(pk0.x);
                a2 += b2f_lo(pk0.y); a3 += b2f_hi(pk0.y);
                a4 += b2f_lo(pk0.z); a5 += b2f_hi(pk0.z);
                a6 += b2f_lo(pk0.w); a7 += b2f_hi(pk0.w);

                if (cw0 >> 16) {
                    int v = (int)(cw0 >> 16) - 1;
                    float r0 = fmaxf(fmaf(a0, fdv0, bv0.x), 0.f);
                    float r1 = fmaxf(fmaf(a1, fdv0, bv0.y), 0.f);
                    float r2 = fmaxf(fmaf(a2, fdv0, bv0.z), 0.f);
                    float r3 = fmaxf(fmaf(a3, fdv0, bv0.w), 0.f);
                    float r4 = fmaxf(fmaf(a4, fdv0, bv1.x), 0.f);
                    float r5 = fmaxf(fmaf(a5, fdv0, bv1.y), 0.f);
                    float r6 = fmaxf(fmaf(a6, fdv0, bv1.z), 0.f);
                    float r7 = fmaxf(fmaf(a7, fdv0, bv1.w), 0.f);
                    uint4 u;
                    u.x = (uint)f2b(r0) | ((uint)f2b(r1) << 16);
                    u.y = (uint)f2b(r2) | ((uint)f2b(r3) << 16);
                    u.z = (uint)f2b(r4) | ((uint)f2b(r5) << 16);
                    u.w = (uint)f2b(r6) | ((uint)f2b(r7) << 16);
                    *(uint4*)(outp + (size_t)v * 128 + s * 32 + q * 8) = u;
                    a0 = a1 = a2 = a3 = a4 = a5 = a6 = a7 = 0.f;
                    if (g + 1 >= se) alive = false;
                }
                g++; cp++;
                cw0 = cw1; cw1 = cw2; cw2 = cw3; cw3 = cw4;
                pk0 = pk1; pk1 = pk2; pk2 = pk3;
                fdv0 = fdv1; fdv1 = fdv2; fdv2 = fdv3;
            }
        }
    }
}

// ---------------- the single fused kernel (plain launch + software barrier) ----------------

__global__ __launch_bounds__(BLK, 4) void k_fused(Params p) {
    __shared__ __align__(16) char smem[15360];
    uint ep = 0;
    uint* bar = p.bar;
    const int tid = threadIdx.x;
    const int gid = blockIdx.x * BLK + tid;
    const int gsz = GRID * BLK;

    // ---- P0: weight transpose/cast + degree count + ticket (deg pre-zeroed by memset) ----
    for (int idx = gid; idx < (NFEAT + NHID) * 128; idx += gsz) {
        if (idx < NFEAT * 128) {
            int k = idx >> 7, c = idx & 127;
            p.W1T[(size_t)c * NFEAT + k] = f2b(p.W1[idx]);
        } else {
            int j = idx - NFEAT * 128;
            int k = j >> 7, c = j & 127;
            p.W2T[(size_t)c * NHID + k] = f2b(p.W2[j]);
        }
    }
    for (int i = gid; i < p.E; i += gsz)
        p.ticket[i] = atomicAdd(&p.deg[p.dst[i]], 1);     // 0-based edge slot within node
    gsync(bar, ep);

    // ---- P1: per-chunk exclusive scan of (deg+1) + dinv ----
    {
        int* sS = (int*)smem;
        for (int c = blockIdx.x; c < p.nbch; c += GRID) {
            int i = c * BLK + tid;
            int d = (i < p.N) ? (p.deg[i] + 1) : 0;       // +1 self-loop
            if (i < p.N) p.dinv[i] = rsqrtf((float)d);
            sS[tid] = d;
            for (int off = 1; off < BLK; off <<= 1) {
                __syncthreads();
                int x = (tid >= off) ? sS[tid - off] : 0;
                __syncthreads();
                sS[tid] += x;
            }
            __syncthreads();
            if (i < p.N) p.eoffs[i] = sS[tid] - d;
            if (tid == BLK - 1) p.bsum[c] = sS[tid];
            __syncthreads();
        }
    }
    gsync(bar, ep);

    // ---- P2: add chunk prefix (every block re-scans bsum; nbch <= 256) ----
    {
        int* sP = (int*)smem;
        sP[tid] = (tid < p.nbch) ? p.bsum[tid] : 0;
        for (int off = 1; off < BLK; off <<= 1) {
            __syncthreads();
            int x = (tid >= off) ? sP[tid - off] : 0;
            __syncthreads();
            sP[tid] += x;
        }
        __syncthreads();
        for (int c = blockIdx.x; c < p.nbch; c += GRID) {
            int i = c * BLK + tid;
            int add = c ? sP[c - 1] : 0;
            if (i < p.N) p.eoffs[i] += add;
        }
        if (blockIdx.x == 0 && tid == 0) p.eoffs[p.N] = p.S;
    }
    gsync(bar, ep);

    // ---- P3: edge scatter (atomic-free) + self/meta slot + rankgs + pad ----
    for (int i = gid; i < p.E; i += gsz) {
        p.colp32[p.eoffs[p.dst[i]] + p.ticket[i]] = (uint)p.src[i];   // meta 0
        if (i < p.N)
            p.colp32[p.eoffs[i + 1] - 1] = (uint)i | ((uint)(i + 1) << 16);  // self + boundary
        if (i < NSTREAMS) {
            int len = (p.S + NSTREAMS - 1) / NSTREAMS;
            int target = i * len;
            int lo = 0, hi = p.N;
            while (lo < hi) {
                int mid = (lo + hi) >> 1;
                if (p.eoffs[mid] < target) lo = mid + 1; else hi = mid;
            }
            p.rankgs[i] = p.eoffs[lo];
            if (i == 0) p.rankgs[NSTREAMS] = p.S;
        }
        if (i == 0) {
#pragma unroll
            for (int k = 0; k < 8; k++) p.colp32[p.S + k] = 0;
        }
    }
    gsync(bar, ep);

    // ---- P4: GEMM layer 1 ----
    gemm_phase<1>(p.x, p.W1T, p.dinv, p.hs, p.N, NFEAT, p.gtiles, smem);
    gsync(bar, ep);

    // ---- P5: aggregation layer 1 ----
    aggs_phase(p.hs, p.colp32, p.rankgs, p.dinv, p.b1, p.g1, p.N);
    gsync(bar, ep);

    // ---- P6: GEMM layer 2 ----
    gemm_phase<0>(p.g1, p.W2T, p.dinv, p.hs, p.N, NHID, p.gtiles, smem);
    gsync(bar, ep);

    // ---- P7: aggregation layer 2 ----
    aggs_phase(p.hs, p.colp32, p.rankgs, p.dinv, p.b2, p.g2, p.N);
    gsync(bar, ep);

    // ---- P8: classifier + log_softmax ----
    {
        float* Ws = (float*)smem;
#pragma unroll
        for (int t = 0; t < 8; t++) Ws[tid + 256 * t] = p.Wc[tid + 256 * t];
        __syncthreads();

        int wid = tid >> 6, lane = tid & 63;
        int j = lane & 15, c = lane >> 4;
        int nblocks = (p.N + 3) / 4;
        for (int bb = blockIdx.x; bb < nblocks; bb += GRID) {
            int v = bb * 4 + wid;
            if (v < p.N) {
                const ushort* hv = p.g2 + (size_t)v * 128 + c * 32;
                float acc = 0.f;
#pragma unroll
                for (int t = 0; t < 16; t++) {
                    uint pk = *(const uint*)(hv + t * 2);
                    acc = fmaf(b2f_lo(pk), Ws[(c * 32 + t * 2 + 0) * 16 + j], acc);
                    acc = fmaf(b2f_hi(pk), Ws[(c * 32 + t * 2 + 1) * 16 + j], acc);
                }
                acc += __shfl_xor(acc, 16);
                acc += __shfl_xor(acc, 32);
                acc += p.bc[j];

                float m = acc;
#pragma unroll
                for (int o = 8; o >= 1; o >>= 1) m = fmaxf(m, __shfl_xor(m, o));
                float sum = expf(acc - m);
#pragma unroll
                for (int o = 8; o >= 1; o >>= 1) sum += __shfl_xor(sum, o);
                if (lane < 16) p.out[(size_t)v * 16 + j] = acc - m - logf(sum);
            }
        }
    }
}

// ---------------- launch ----------------

extern "C" void kernel_launch(void* const* d_in, const int* in_sizes, int n_in,
                              void* d_out, int out_size, void* d_ws, size_t ws_size,
                              hipStream_t stream) {
    const int N = in_sizes[0] / NFEAT;   // 50000 (< 65536 -> 16-bit node ids)
    const int E = in_sizes[1] / 2;       // 800000
    const int S = E + N;

    Params p;
    p.x   = (const float*)d_in[0];
    p.src = (const int*)d_in[1];
    p.dst = (const int*)d_in[1] + E;
    p.W1 = (const float*)d_in[2];
    p.b1 = (const float*)d_in[3];
    p.W2 = (const float*)d_in[4];
    p.b2 = (const float*)d_in[5];
    p.Wc = (const float*)d_in[6];
    p.bc = (const float*)d_in[7];
    p.out = (float*)d_out;
    p.N = N; p.E = E; p.S = S;
    p.nbch = (N + BLK - 1) / BLK;        // 196 <= 256
    p.gtiles = (N + 63) / 64;            // 782

    char* w = (char*)d_ws;
    auto alloc = [&](size_t bytes) { char* r = w; w += (bytes + 255) & ~(size_t)255; return r; };
    p.bar    = (uint*)  alloc(256);                    // barrier state (zeroed below)
    p.deg    = (int*)   alloc((size_t)N * 4);          // zeroed below (contiguous with bar)
    p.dinv   = (float*) alloc((size_t)N * 4);
    p.eoffs  = (int*)   alloc((size_t)(N + 1) * 4);
    p.ticket = (int*)   alloc((size_t)E * 4);
    p.colp32 = (uint*)  alloc(((size_t)S + 16) * 4);
    p.rankgs = (int*)   alloc((size_t)(NSTREAMS + 1) * 4);
    p.bsum   = (int*)   alloc((size_t)256 * 4);
    p.W1T    = (ushort*)alloc((size_t)128 * NFEAT * 2);
    p.W2T    = (ushort*)alloc((size_t)128 * NHID * 2);
    p.hs     = (ushort*)alloc((size_t)N * NHID * 2);
    p.g1     = (ushort*)alloc((size_t)N * NHID * 2);
    p.g2     = (ushort*)alloc((size_t)N * NHID * 2);

    // zero barrier state + deg in one async memset (capture-legal)
    hipMemsetAsync(p.bar, 0, 256 + (size_t)N * 4, stream);

    k_fused<<<GRID, BLK, 0, stream>>>(p);
}

// Round 14
// 228.806 us; speedup vs baseline: 4.5860x; 4.5860x over previous
//
#include <hip/hip_runtime.h>
#include <math.h>

#define NFEAT 512
#define NHID  128
#define NCLASS 16
#define SCAN_BS 512
#define AGG_BLOCKS 1024   // 256 blocks per slice (slice = b&3)
#define NSTREAMS 16384    // 1024 blocks x 4 waves x 16 streams

typedef __attribute__((ext_vector_type(8))) short short8;
typedef __attribute__((ext_vector_type(4))) float f32x4;

static __device__ __forceinline__ ushort f2b(float f) {
    union { float f; uint u; } v; v.f = f;
    uint r = v.u + 0x7FFFu + ((v.u >> 16) & 1u);   // round-to-nearest-even
    return (ushort)(r >> 16);
}
static __device__ __forceinline__ float b2f_lo(uint bits) {
    union { uint u; float f; } v; v.u = bits << 16; return v.f;
}
static __device__ __forceinline__ float b2f_hi(uint bits) {
    union { uint u; float f; } v; v.u = bits & 0xffff0000u; return v.f;
}

// ---------------- init: deg=1 (self-loop) + weight transpose/cast ----------

__global__ void k_init_tcast(const float* __restrict__ W1, const float* __restrict__ W2,
                             ushort* __restrict__ W1T, ushort* __restrict__ W2T,
                             int* __restrict__ deg, int n) {
    int idx = blockIdx.x * 256 + threadIdx.x;
    if (idx < n) deg[idx] = 1;
    if (idx < NFEAT * 128) {
        int k = idx >> 7, c = idx & 127;
        W1T[(size_t)c * NFEAT + k] = f2b(W1[idx]);
    } else {
        int j = idx - NFEAT * 128;
        if (j < NHID * 128) {
            int k = j >> 7, c = j & 127;
            W2T[(size_t)c * NHID + k] = f2b(W2[j]);
        }
    }
}

// count + ticket: atomic return value = slot index within node (1-based; deg starts at 1)
__global__ void k_count(const int* __restrict__ dst, int e, int* __restrict__ deg,
                        int* __restrict__ ticket) {
    int i = blockIdx.x * blockDim.x + threadIdx.x;
    if (i < e) ticket[i] = atomicAdd(&deg[dst[i]], 1);
}

// chunk-local exclusive scan of deg (chunk = SCAN_BS) + chunk sums + dinv
__global__ void k_scan1(const int* __restrict__ deg, float* __restrict__ dinv,
                        int* __restrict__ offs, int* __restrict__ bsum, int n) {
    __shared__ int s[SCAN_BS];
    int t = threadIdx.x;
    int i = blockIdx.x * SCAN_BS + t;
    int d = (i < n) ? deg[i] : 0;
    if (i < n) dinv[i] = rsqrtf((float)d);
    s[t] = d;
    for (int off = 1; off < SCAN_BS; off <<= 1) {
        __syncthreads();
        int x = (t >= off) ? s[t - off] : 0;
        __syncthreads();
        s[t] += x;
    }
    __syncthreads();
    if (i < n) offs[i] = s[t] - d;          // chunk-local exclusive
    if (t == SCAN_BS - 1) bsum[blockIdx.x] = s[t];
}

// edge scatter (atomic-free via ticket) + self/meta slot + rankgs + pad.
// offs is chunk-local; each block rebuilds the <=128-chunk prefix in smem.
__global__ void k_fill_edges(const int* __restrict__ src, const int* __restrict__ dst, int e,
                             const int* __restrict__ offs, const int* __restrict__ bsum,
                             const int* __restrict__ ticket, uint* __restrict__ colp32,
                             int* __restrict__ rankgs, int n, int S, int nbch) {
    __shared__ int incl[128];
    int tid = threadIdx.x;
    if (tid < 64) {
        int carry = 0;
        for (int base = 0; base < nbch; base += 64) {
            int j = base + tid;
            int v = (j < nbch) ? bsum[j] : 0;
            for (int off = 1; off < 64; off <<= 1) {
                int x = __shfl_up(v, off);
                if (tid >= off) v += x;
            }
            if (j < nbch) incl[j] = carry + v;   // inclusive chunk prefix
            carry += __shfl(v, 63);
        }
    }
    __syncthreads();

    auto absoff = [&](int v) -> int {
        if (v >= n) return S;
        int c = v >> 9;                           // SCAN_BS = 512
        return offs[v] + (c ? incl[c - 1] : 0);
    };

    int i = blockIdx.x * blockDim.x + tid;
    if (i < e) {
        colp32[absoff(dst[i]) + ticket[i] - 1] = (uint)src[i];   // meta 0
    }
    if (i < n) {
        colp32[absoff(i + 1) - 1] = (uint)i | ((uint)(i + 1) << 16);  // self-loop + boundary
    }
    if (i < NSTREAMS) {
        int len = (S + NSTREAMS - 1) / NSTREAMS;
        int target = i * len;
        int lo = 0, hi = n;
        while (lo < hi) {                         // first v with absoff(v) >= target
            int mid = (lo + hi) >> 1;
            if (absoff(mid) < target) lo = mid + 1; else hi = mid;
        }
        rankgs[i] = absoff(lo);
        if (i == 0) rankgs[NSTREAMS] = S;
    }
    if (i == 0) {
#pragma unroll
        for (int k = 0; k < 8; k++) colp32[S + k] = 0;   // prefetch pad
    }
}

// ---------------- bf16 MFMA GEMM, 64x128 tile -> 4-slice output ----------------
// 4 waves; wave wc owns output cols [wc*32, wc*32+32) = slice wc.
// Hs layout: [slice(4)][node(M)][32 feats] bf16, pre-scaled by rowscale[row].

template<int A_F32>
__global__ __launch_bounds__(256) void k_gemm(const void* __restrict__ Aptr,
                                              const ushort* __restrict__ WT,
                                              const float* __restrict__ rowscale,
                                              ushort* __restrict__ Hs, int M, int K) {
    __shared__ ushort As[64][40];   // pad 40: <=2-way bank conflict (free)
    __shared__ ushort Bs[128][40];

    const int tid = threadIdx.x;
    const int wc = tid >> 6, lane = tid & 63;
    const int lr = lane & 15, lk = (lane >> 4) * 8;
    const int rowbase = blockIdx.x * 64;

    f32x4 acc[4][2];
#pragma unroll
    for (int i = 0; i < 4; i++)
#pragma unroll
        for (int j = 0; j < 2; j++) acc[i][j] = (f32x4)0.f;

    const int sr = tid >> 2;        // staging row 0..63
    const int sh = (tid & 3) * 8;   // staging octet

    for (int k0 = 0; k0 < K; k0 += 32) {
        {
            int gr = rowbase + sr;
            ushort tmp[8];
            if (A_F32) {
                const float* A = (const float*)Aptr;
                if (gr < M) {
                    const float* p = A + (size_t)gr * K + k0 + sh;
#pragma unroll
                    for (int q = 0; q < 2; q++) {
                        float4 v = *(const float4*)(p + q * 4);
                        tmp[q * 4 + 0] = f2b(v.x); tmp[q * 4 + 1] = f2b(v.y);
                        tmp[q * 4 + 2] = f2b(v.z); tmp[q * 4 + 3] = f2b(v.w);
                    }
                } else {
#pragma unroll
                    for (int q = 0; q < 8; q++) tmp[q] = 0;
                }
            } else {
                const ushort* A = (const ushort*)Aptr;
                if (gr < M) {
                    *(short8*)&tmp[0] = *(const short8*)(A + (size_t)gr * K + k0 + sh);
                } else {
#pragma unroll
                    for (int q = 0; q < 8; q++) tmp[q] = 0;
                }
            }
            *(short8*)&As[sr][sh] = *(short8*)&tmp[0];
        }
        {
#pragma unroll
            for (int t = 0; t < 2; t++) {
                int c = tid + t * 256;
                int row = c >> 2, q = c & 3;
                short8 v = *(const short8*)(WT + (size_t)row * K + k0 + q * 8);
                *(short8*)&Bs[row][q * 8] = v;
            }
        }
        __syncthreads();

        short8 af[4], bfv[2];
#pragma unroll
        for (int i = 0; i < 4; i++) af[i] = *(const short8*)&As[i * 16 + lr][lk];
#pragma unroll
        for (int j = 0; j < 2; j++) bfv[j] = *(const short8*)&Bs[wc * 32 + j * 16 + lr][lk];
#pragma unroll
        for (int i = 0; i < 4; i++)
#pragma unroll
            for (int j = 0; j < 2; j++)
                acc[i][j] = __builtin_amdgcn_mfma_f32_16x16x32_bf16(af[i], bfv[j], acc[i][j], 0, 0, 0);
        __syncthreads();
    }

#pragma unroll
    for (int i = 0; i < 4; i++) {
#pragma unroll
        for (int r = 0; r < 4; r++) {
            int row = rowbase + i * 16 + (lane >> 4) * 4 + r;
            if (row < M) {
                float sc = rowscale[row];
#pragma unroll
                for (int j = 0; j < 2; j++) {
                    int f = j * 16 + lr;
                    Hs[((size_t)wc * M + row) * 32 + f] = f2b(acc[i][j][r] * sc);
                }
            }
        }
    }
}

// ---------------- stream-parallel segmented aggregation, depth-5 pipeline ----------------
// 16 streams per wave (4 lanes x 16B each); stream owns exact node range
// [rankgs[r], rankgs[r+1]); flush at node boundary (meta word), no cross-lane reduce.

__global__ __launch_bounds__(256) void k_aggs(const ushort* __restrict__ hs,
                                              const uint* __restrict__ colp32,
                                              const int* __restrict__ rankgs,
                                              const float* __restrict__ dinv,
                                              const float* __restrict__ bias,
                                              ushort* __restrict__ outp, int n) {
    const int b = blockIdx.x;
    const int s = b & 3;                          // slice, pinned to XCDs {s, s+4}
    const int wid = threadIdx.x >> 6, lane = threadIdx.x & 63;
    const int st16 = lane >> 2, q = lane & 3;     // stream-in-wave, feat-quad (16B)
    const int stream = (((b >> 2) << 2) + wid) * 16 + st16;
    int g = rankgs[stream];
    int se = rankgs[stream + 1];
    bool alive = g < se;
    if (!alive) g = 0;

    const ushort* hsl = hs + (size_t)s * n * 32;
    const float4 bv0 = *(const float4*)(bias + s * 32 + q * 8);
    const float4 bv1 = *(const float4*)(bias + s * 32 + q * 8 + 4);

    const uint* cp = colp32 + g;
    uint cw0 = cp[0], cw1 = cp[1], cw2 = cp[2], cw3 = cp[3], cw4 = cp[4];
    uint4 pk0 = *(const uint4*)(hsl + (size_t)(cw0 & 0xffffu) * 32 + q * 8);
    uint4 pk1 = *(const uint4*)(hsl + (size_t)(cw1 & 0xffffu) * 32 + q * 8);
    uint4 pk2 = *(const uint4*)(hsl + (size_t)(cw2 & 0xffffu) * 32 + q * 8);
    uint4 pk3 = *(const uint4*)(hsl + (size_t)(cw3 & 0xffffu) * 32 + q * 8);
    float fdv0 = (cw0 >> 16) ? dinv[(cw0 >> 16) - 1] : 0.f;
    float fdv1 = (cw1 >> 16) ? dinv[(cw1 >> 16) - 1] : 0.f;
    float fdv2 = (cw2 >> 16) ? dinv[(cw2 >> 16) - 1] : 0.f;
    float fdv3 = (cw3 >> 16) ? dinv[(cw3 >> 16) - 1] : 0.f;
    float a0 = 0.f, a1 = 0.f, a2 = 0.f, a3 = 0.f;
    float a4 = 0.f, a5 = 0.f, a6 = 0.f, a7 = 0.f;

    while (__any(alive)) {
        if (alive) {
            uint cw5 = cp[5];
            uint4 pk4 = *(const uint4*)(hsl + (size_t)(cw4 & 0xffffu) * 32 + q * 8);
            float fdv4 = (cw4 >> 16) ? dinv[(cw4 >> 16) - 1] : 0.f;

            a0 += b2f_lo(pk0.x); a1 += b2f_hi(pk0.x);
            a2 += b2f_lo(pk0.y); a3 += b2f_hi(pk0.y);
            a4 += b2f_lo(pk0.z); a5 += b2f_hi(pk0.z);
            a6 += b2f_lo(pk0.w); a7 += b2f_hi(pk0.w);

            if (cw0 >> 16) {   // node boundary (per-stream, exec-masked)
                int v = (int)(cw0 >> 16) - 1;
                float r0 = fmaxf(fmaf(a0, fdv0, bv0.x), 0.f);
                float r1 = fmaxf(fmaf(a1, fdv0, bv0.y), 0.f);
                float r2 = fmaxf(fmaf(a2, fdv0, bv0.z), 0.f);
                float r3 = fmaxf(fmaf(a3, fdv0, bv0.w), 0.f);
                float r4 = fmaxf(fmaf(a4, fdv0, bv1.x), 0.f);
                float r5 = fmaxf(fmaf(a5, fdv0, bv1.y), 0.f);
                float r6 = fmaxf(fmaf(a6, fdv0, bv1.z), 0.f);
                float r7 = fmaxf(fmaf(a7, fdv0, bv1.w), 0.f);
                uint4 u;
                u.x = (uint)f2b(r0) | ((uint)f2b(r1) << 16);
                u.y = (uint)f2b(r2) | ((uint)f2b(r3) << 16);
                u.z = (uint)f2b(r4) | ((uint)f2b(r5) << 16);
                u.w = (uint)f2b(r6) | ((uint)f2b(r7) << 16);
                *(uint4*)(outp + (size_t)v * 128 + s * 32 + q * 8) = u;
                a0 = a1 = a2 = a3 = a4 = a5 = a6 = a7 = 0.f;
                if (g + 1 >= se) alive = false;
            }
            g++; cp++;
            cw0 = cw1; cw1 = cw2; cw2 = cw3; cw3 = cw4; cw4 = cw5;
            pk0 = pk1; pk1 = pk2; pk2 = pk3; pk3 = pk4;
            fdv0 = fdv1; fdv1 = fdv2; fdv2 = fdv3; fdv3 = fdv4;
        }
    }
}

// ---------------- classifier + log_softmax (bf16 hidden input, row-major) ----------------

__global__ __launch_bounds__(256) void k_classify(const ushort* __restrict__ h,
                                                  const float* __restrict__ Wc,
                                                  const float* __restrict__ bc,
                                                  float* __restrict__ out, int n) {
    __shared__ float Ws[128 * 16];
    int tid = threadIdx.x;
#pragma unroll
    for (int t = 0; t < 8; t++) Ws[tid + 256 * t] = Wc[tid + 256 * t];
    __syncthreads();

    int wid = tid >> 6, lane = tid & 63;
    int v = blockIdx.x * 4 + wid;
    if (v >= n) return;

    int j = lane & 15, c = lane >> 4;
    const ushort* hv = h + (size_t)v * 128 + c * 32;
    float acc = 0.f;
#pragma unroll
    for (int t = 0; t < 16; t++) {
        uint pk = *(const uint*)(hv + t * 2);
        acc = fmaf(b2f_lo(pk), Ws[(c * 32 + t * 2 + 0) * 16 + j], acc);
        acc = fmaf(b2f_hi(pk), Ws[(c * 32 + t * 2 + 1) * 16 + j], acc);
    }
    acc += __shfl_xor(acc, 16);
    acc += __shfl_xor(acc, 32);
    acc += bc[j];

    float m = acc;
#pragma unroll
    for (int o = 8; o >= 1; o >>= 1) m = fmaxf(m, __shfl_xor(m, o));
    float sum = expf(acc - m);
#pragma unroll
    for (int o = 8; o >= 1; o >>= 1) sum += __shfl_xor(sum, o);
    if (lane < 16) out[(size_t)v * 16 + j] = acc - m - logf(sum);
}

// ---------------- launch ----------------

extern "C" void kernel_launch(void* const* d_in, const int* in_sizes, int n_in,
                              void* d_out, int out_size, void* d_ws, size_t ws_size,
                              hipStream_t stream) {
    const float* x  = (const float*)d_in[0];
    const int* eidx = (const int*)d_in[1];
    const float* W1 = (const float*)d_in[2];
    const float* b1 = (const float*)d_in[3];
    const float* W2 = (const float*)d_in[4];
    const float* b2 = (const float*)d_in[5];
    const float* Wc = (const float*)d_in[6];
    const float* bc = (const float*)d_in[7];
    float* out = (float*)d_out;

    const int N = in_sizes[0] / NFEAT;   // 50000 (< 65536 -> 16-bit node ids)
    const int E = in_sizes[1] / 2;       // 800000
    const int S = E + N;                 // total slots (no padding)
    const int* src = eidx;
    const int* dst = eidx + E;

    char* p = (char*)d_ws;
    auto alloc = [&](size_t bytes) { char* r = p; p += (bytes + 255) & ~(size_t)255; return r; };
    int*    deg    = (int*)   alloc((size_t)N * 4);
    float*  dinv   = (float*) alloc((size_t)N * 4);
    int*    eoffs  = (int*)   alloc((size_t)(N + 1) * 4);
    int*    ticket = (int*)   alloc((size_t)E * 4);
    uint*   colp32 = (uint*)  alloc(((size_t)S + 16) * 4);
    int*    rankgs = (int*)   alloc((size_t)(NSTREAMS + 1) * 4);
    int*    bsum   = (int*)   alloc((size_t)256 * 4);
    ushort* W1T    = (ushort*)alloc((size_t)128 * NFEAT * 2);
    ushort* W2T    = (ushort*)alloc((size_t)128 * NHID * 2);
    ushort* hs     = (ushort*)alloc((size_t)N * NHID * 2);   // 4 slices x N x 32
    ushort* g1     = (ushort*)alloc((size_t)N * NHID * 2);   // agg1 out, row-major bf16
    ushort* g2     = (ushort*)alloc((size_t)N * NHID * 2);   // agg2 out, row-major bf16

    const int nb = (N + SCAN_BS - 1) / SCAN_BS;   // 98 <= 128

    k_init_tcast<<<((NFEAT + NHID) * 128 + 255) / 256, 256, 0, stream>>>(W1, W2, W1T, W2T, deg, N);
    k_count<<<(E + 255) / 256, 256, 0, stream>>>(dst, E, deg, ticket);
    k_scan1<<<nb, SCAN_BS, 0, stream>>>(deg, dinv, eoffs, bsum, N);
    k_fill_edges<<<(E + 255) / 256, 256, 0, stream>>>(src, dst, E, eoffs, bsum, ticket,
                                                      colp32, rankgs, N, S, nb);

    const int gblocks = (N + 63) / 64;
    // layer 1
    k_gemm<1><<<gblocks, 256, 0, stream>>>(x, W1T, dinv, hs, N, NFEAT);
    k_aggs<<<AGG_BLOCKS, 256, 0, stream>>>(hs, colp32, rankgs, dinv, b1, g1, N);
    // layer 2
    k_gemm<0><<<gblocks, 256, 0, stream>>>(g1, W2T, dinv, hs, N, NHID);
    k_aggs<<<AGG_BLOCKS, 256, 0, stream>>>(hs, colp32, rankgs, dinv, b2, g2, N);
    // classifier
    k_classify<<<(N + 3) / 4, 256, 0, stream>>>(g2, Wc, bc, out, N);
}